// Round 4
// baseline (127.937 us; speedup 1.0000x reference)
//
#include <hip/hip_runtime.h>
#include <stdint.h>
#include <stddef.h>

// Problem constants (fixed by the reference).
#define BSZ  256
#define NSZ  4096
#define CIN  8
#define KNB  9
#define DOUT 8
#define NSUB 2

typedef __fp16   fh2  __attribute__((ext_vector_type(2)));   // builtin-compatible half2
typedef float    f4   __attribute__((ext_vector_type(4)));
typedef uint32_t u32x4 __attribute__((ext_vector_type(4)));

static __device__ __forceinline__ uint32_t pk_f16(float a, float b) {
    fh2 h = __builtin_amdgcn_cvt_pkrtz(a, b);   // v_cvt_pkrtz_f16_f32
    return __builtin_bit_cast(uint32_t, h);
}

static __device__ __forceinline__ float dot2(uint32_t a, uint32_t b, float c) {
#if __has_builtin(__builtin_amdgcn_fdot2)
    return __builtin_amdgcn_fdot2(__builtin_bit_cast(fh2, a),
                                  __builtin_bit_cast(fh2, b), c, false);
#else
    fh2 x = __builtin_bit_cast(fh2, a), y = __builtin_bit_cast(fh2, b);
    return c + (float)x[0] * (float)y[0] + (float)x[1] * (float)y[1];
#endif
}

// Pack weight (S,CIN,KNB,DOUT) fp32 -> wp[s][k][cp][d] : u32 = (f16 w[2cp], f16 w[2cp+1])
__global__ void pack_w_kernel(const float* __restrict__ w, uint32_t* __restrict__ wp) {
    int i = threadIdx.x;
    if (i >= NSUB * KNB * 4 * DOUT) return;
    int d = i & 7, cp = (i >> 3) & 3, r = i >> 5;
    int k = r % KNB, s = r / KNB;
    float w0 = w[((s * CIN + 2 * cp    ) * KNB + k) * DOUT + d];
    float w1 = w[((s * CIN + 2 * cp + 1) * KNB + k) * DOUT + d];
    wp[i] = pk_f16(w0, w1);
}

__global__ __launch_bounds__(1024) void latconv_kernel(
    const float* __restrict__ x, const int* __restrict__ nbh,
    const int* __restrict__ sub, const uint32_t* __restrict__ wp,
    const float* __restrict__ bias, float* __restrict__ out)
{
    // xl[j][cp] : 8 channels of column j as 4 packed fp16 pairs (16B row) = 64 KiB
    __shared__ __align__(16) uint32_t xl[NSZ * 4];

    const int b = blockIdx.x;
    const int t = threadIdx.x;
    const float* xb = x + (size_t)b * (CIN * NSZ);

    // ---- stage x[b] -> LDS (fp32 -> packed fp16, transpose to [j][c]) ----
    {
        const int j0 = 4 * t;                    // this thread owns columns j0..j0+3
        f4 v[CIN];
        #pragma unroll
        for (int c = 0; c < CIN; ++c)
            v[c] = *reinterpret_cast<const f4*>(xb + c * NSZ + j0);   // coalesced 16B
        #pragma unroll
        for (int jj = 0; jj < 4; ++jj) {
            u32x4 row;
            #pragma unroll
            for (int cp = 0; cp < 4; ++cp)
                row[cp] = pk_f16(v[2 * cp][jj], v[2 * cp + 1][jj]);
            *reinterpret_cast<u32x4*>(&xl[(size_t)(j0 + jj) * 4]) = row;  // ds_write_b128
        }
    }

    // bias rows for both sites (uniform scalar loads)
    float bias0[DOUT], bias1[DOUT];
    #pragma unroll
    for (int d = 0; d < DOUT; ++d) { bias0[d] = bias[d]; bias1[d] = bias[DOUT + d]; }

    // ---- per-thread n-range: 4 consecutive n ----
    const int n0 = 4 * t;

    const int4 s4 = *reinterpret_cast<const int4*>(sub + n0);
    const int sv[4] = { s4.x, s4.y, s4.z, s4.w };

    // neighbor indices for 4 rows of K=9: 36 contiguous ints, 16B-aligned (n0*9*4 = 144*t)
    uint32_t ja[4][KNB];   // LDS byte addresses
    {
        int4 q[9];
        const int4* np4 = reinterpret_cast<const int4*>(nbh + (size_t)n0 * KNB);
        #pragma unroll
        for (int r = 0; r < 9; ++r) q[r] = np4[r];
        const int* qs = reinterpret_cast<const int*>(q);
        #pragma unroll
        for (int i = 0; i < 4; ++i)
            #pragma unroll
            for (int k = 0; k < KNB; ++k)
                ja[i][k] = (uint32_t)qs[i * KNB + k] << 4;   // j * 16 bytes
    }

    float acc[4][DOUT];
    #pragma unroll
    for (int i = 0; i < 4; ++i)
        #pragma unroll
        for (int d = 0; d < DOUT; ++d)
            acc[i][d] = sv[i] ? bias1[d] : bias0[d];

    __syncthreads();

    const char* xlb = reinterpret_cast<const char*>(xl);
    for (int k = 0; k < KNB; ++k) {
        // gather 4 neighbor columns from LDS (one b128 each: all 8 channels)
        u32x4 xv[4];
        #pragma unroll
        for (int i = 0; i < 4; ++i)
            xv[i] = *reinterpret_cast<const u32x4*>(xlb + ja[i][k]);
        #pragma unroll
        for (int cp = 0; cp < 4; ++cp) {
            const uint32_t* w0p = wp + ((0 * KNB + k) * 4 + cp) * 8;
            const uint32_t* w1p = wp + ((1 * KNB + k) * 4 + cp) * 8;
            uint32_t wq0[DOUT], wq1[DOUT];
            #pragma unroll
            for (int d = 0; d < DOUT; ++d) { wq0[d] = w0p[d]; wq1[d] = w1p[d]; }
            #pragma unroll
            for (int i = 0; i < 4; ++i) {
                #pragma unroll
                for (int d = 0; d < DOUT; ++d) {
                    const uint32_t wsel = sv[i] ? wq1[d] : wq0[d];   // v_cndmask
                    acc[i][d] = dot2(xv[i][cp], wsel, acc[i][d]);    // v_dot2_f32_f16
                }
            }
        }
    }

    // coalesced stores: per d, 4 consecutive n per lane -> contiguous 1KB per wave
    #pragma unroll
    for (int d = 0; d < DOUT; ++d) {
        f4 o = { acc[0][d], acc[1][d], acc[2][d], acc[3][d] };
        *reinterpret_cast<f4*>(out + ((size_t)b * DOUT + d) * NSZ + n0) = o;
    }
}

extern "C" void kernel_launch(void* const* d_in, const int* in_sizes, int n_in,
                              void* d_out, int out_size, void* d_ws, size_t ws_size,
                              hipStream_t stream) {
    const float* x    = (const float*)d_in[0];
    const int*   nbh  = (const int*)d_in[1];
    const int*   sub  = (const int*)d_in[2];
    const float* w    = (const float*)d_in[3];
    const float* bias = (const float*)d_in[4];
    float* out = (float*)d_out;
    uint32_t* wp = (uint32_t*)d_ws;   // 2304 B packed-weight table

    pack_w_kernel<<<1, 576, 0, stream>>>(w, wp);
    latconv_kernel<<<BSZ, 1024, 0, stream>>>(x, nbh, sub, wp, bias, out);
}

// Round 5
// 120.859 us; speedup vs baseline: 1.0586x; 1.0586x over previous
//
#include <hip/hip_runtime.h>
#include <stdint.h>
#include <stddef.h>

// Problem constants (fixed by the reference).
#define BSZ  256
#define NSZ  4096
#define CIN  8
#define KNB  9
#define DOUT 8
#define NSUB 2

typedef __fp16   fh2  __attribute__((ext_vector_type(2)));   // builtin-compatible half2
typedef float    f2   __attribute__((ext_vector_type(2)));
typedef float    f4   __attribute__((ext_vector_type(4)));
typedef int      i2   __attribute__((ext_vector_type(2)));
typedef uint32_t u32x4 __attribute__((ext_vector_type(4)));

static __device__ __forceinline__ uint32_t pk_f16(float a, float b) {
    fh2 h = __builtin_amdgcn_cvt_pkrtz(a, b);   // v_cvt_pkrtz_f16_f32
    return __builtin_bit_cast(uint32_t, h);
}

static __device__ __forceinline__ float dot2(uint32_t a, uint32_t b, float c) {
#if __has_builtin(__builtin_amdgcn_fdot2)
    return __builtin_amdgcn_fdot2(__builtin_bit_cast(fh2, a),
                                  __builtin_bit_cast(fh2, b), c, false);
#else
    fh2 x = __builtin_bit_cast(fh2, a), y = __builtin_bit_cast(fh2, b);
    return c + (float)x[0] * (float)y[0] + (float)x[1] * (float)y[1];
#endif
}

// Pack weight (S,CIN,KNB,DOUT) fp32 -> wp[s][k][cp][d] : u32 = (f16 w[2cp], f16 w[2cp+1])
__global__ void pack_w_kernel(const float* __restrict__ w, uint32_t* __restrict__ wp) {
    int i = threadIdx.x;
    if (i >= NSUB * KNB * 4 * DOUT) return;
    int d = i & 7, cp = (i >> 3) & 3, r = i >> 5;
    int k = r % KNB, s = r / KNB;
    float w0 = w[((s * CIN + 2 * cp    ) * KNB + k) * DOUT + d];
    float w1 = w[((s * CIN + 2 * cp + 1) * KNB + k) * DOUT + d];
    wp[i] = pk_f16(w0, w1);
}

// grid = 512: block bid handles b = bid%256, n-half = bid/256.
// Each block stages ALL of x[b] (gather may touch any column) but computes
// only 2048 outputs (2 n per thread). 64 KiB LDS -> 2 blocks/CU resident.
__global__ __launch_bounds__(1024) void latconv_kernel(
    const float* __restrict__ x, const int* __restrict__ nbh,
    const int* __restrict__ sub, const uint32_t* __restrict__ wp,
    const float* __restrict__ bias, float* __restrict__ out)
{
    // xl[j][cp] : 8 channels of column j as 4 packed fp16 pairs (16B row) = 64 KiB
    __shared__ __align__(16) uint32_t xl[NSZ * 4];

    const int b    = blockIdx.x & 255;
    const int half = blockIdx.x >> 8;          // same-XCD pairing: bid and bid+256
    const int t    = threadIdx.x;
    const float* xb = x + (size_t)b * (CIN * NSZ);

    // ---- stage x[b] -> LDS (fp32 -> packed fp16, transpose to [j][c]) ----
    {
        const int j0 = 4 * t;                  // this thread stages columns j0..j0+3
        f4 v[CIN];
        #pragma unroll
        for (int c = 0; c < CIN; ++c)
            v[c] = *reinterpret_cast<const f4*>(xb + c * NSZ + j0);   // coalesced 16B
        #pragma unroll
        for (int jj = 0; jj < 4; ++jj) {
            u32x4 row;
            #pragma unroll
            for (int cp = 0; cp < 4; ++cp)
                row[cp] = pk_f16(v[2 * cp][jj], v[2 * cp + 1][jj]);
            *reinterpret_cast<u32x4*>(&xl[(size_t)(j0 + jj) * 4]) = row;  // ds_write_b128
        }
    }

    // bias rows for both sites (uniform scalar loads)
    float bias0[DOUT], bias1[DOUT];
    #pragma unroll
    for (int d = 0; d < DOUT; ++d) { bias0[d] = bias[d]; bias1[d] = bias[DOUT + d]; }

    // ---- per-thread n-range: 2 consecutive n in this block's half ----
    const int n0 = 2 * t + 2048 * half;

    const i2 s2 = *reinterpret_cast<const i2*>(sub + n0);
    const int sv[2] = { s2[0], s2[1] };

    // neighbor indices: 18 contiguous ints, 8B-aligned (offset 72*t bytes)
    uint32_t ja[2][KNB];   // LDS byte addresses
    {
        i2 q[KNB];
        const i2* np2 = reinterpret_cast<const i2*>(nbh + (size_t)n0 * KNB);
        #pragma unroll
        for (int r = 0; r < KNB; ++r) q[r] = np2[r];
        const int* qs = reinterpret_cast<const int*>(q);
        #pragma unroll
        for (int i = 0; i < 2; ++i)
            #pragma unroll
            for (int k = 0; k < KNB; ++k)
                ja[i][k] = (uint32_t)qs[i * KNB + k] << 4;   // j * 16 bytes
    }

    float acc[2][DOUT];
    #pragma unroll
    for (int i = 0; i < 2; ++i)
        #pragma unroll
        for (int d = 0; d < DOUT; ++d)
            acc[i][d] = sv[i] ? bias1[d] : bias0[d];

    __syncthreads();

    const char* xlb = reinterpret_cast<const char*>(xl);
    for (int k = 0; k < KNB; ++k) {
        // gather 2 neighbor columns from LDS (one b128 each: all 8 channels)
        u32x4 xv[2];
        #pragma unroll
        for (int i = 0; i < 2; ++i)
            xv[i] = *reinterpret_cast<const u32x4*>(xlb + ja[i][k]);
        #pragma unroll
        for (int cp = 0; cp < 4; ++cp) {
            const uint32_t* w0p = wp + ((0 * KNB + k) * 4 + cp) * 8;
            const uint32_t* w1p = wp + ((1 * KNB + k) * 4 + cp) * 8;
            uint32_t wq0[DOUT], wq1[DOUT];
            #pragma unroll
            for (int d = 0; d < DOUT; ++d) { wq0[d] = w0p[d]; wq1[d] = w1p[d]; }
            #pragma unroll
            for (int i = 0; i < 2; ++i) {
                #pragma unroll
                for (int d = 0; d < DOUT; ++d) {
                    const uint32_t wsel = sv[i] ? wq1[d] : wq0[d];   // v_cndmask
                    acc[i][d] = dot2(xv[i][cp], wsel, acc[i][d]);    // v_dot2_f32_f16
                }
            }
        }
    }

    // coalesced stores: per d, 2 consecutive n per lane -> contiguous 512B per wave
    #pragma unroll
    for (int d = 0; d < DOUT; ++d) {
        f2 o = { acc[0][d], acc[1][d] };
        *reinterpret_cast<f2*>(out + ((size_t)b * DOUT + d) * NSZ + n0) = o;
    }
}

extern "C" void kernel_launch(void* const* d_in, const int* in_sizes, int n_in,
                              void* d_out, int out_size, void* d_ws, size_t ws_size,
                              hipStream_t stream) {
    const float* x    = (const float*)d_in[0];
    const int*   nbh  = (const int*)d_in[1];
    const int*   sub  = (const int*)d_in[2];
    const float* w    = (const float*)d_in[3];
    const float* bias = (const float*)d_in[4];
    float* out = (float*)d_out;
    uint32_t* wp = (uint32_t*)d_ws;   // 2304 B packed-weight table

    pack_w_kernel<<<1, 576, 0, stream>>>(w, wp);
    latconv_kernel<<<2 * BSZ, 1024, 0, stream>>>(x, nbh, sub, wp, bias, out);
}

// Round 6
// 105.783 us; speedup vs baseline: 1.2094x; 1.1425x over previous
//
#include <hip/hip_runtime.h>
#include <stdint.h>
#include <stddef.h>

// Problem constants (fixed by the reference).
#define BSZ  256
#define NSZ  4096
#define CIN  8
#define KNB  9
#define DOUT 8
#define NSUB 2

typedef __fp16   fh2  __attribute__((ext_vector_type(2)));
typedef __fp16   v8fh __attribute__((ext_vector_type(8)));   // MFMA f16 A/B frag (4 VGPRs)
typedef float    f4   __attribute__((ext_vector_type(4)));
typedef uint32_t u32x4 __attribute__((ext_vector_type(4)));

static __device__ __forceinline__ uint32_t pk_f16(float a, float b) {
    fh2 h = __builtin_amdgcn_cvt_pkrtz(a, b);   // v_cvt_pkrtz_f16_f32
    return __builtin_bit_cast(uint32_t, h);
}

// Build B-fragment table for v_mfma_f32_16x16x32_f16, shape rows=n(16) x cols=d(16,
// only 8 used) x K=96 (k' = kslot*8 + c, kslots 0..11, real kslot<9).
// btab[sg][s][lane] (u32x4): lane: col d=lane&15, kslot = s*4 + (lane>>4); elem e = channel c.
__global__ void pack_bfrag_kernel(const float* __restrict__ w, uint32_t* __restrict__ btab) {
    int t = threadIdx.x;
    if (t >= NSUB * 3 * 64) return;
    int lane = t & 63, s = (t >> 6) % 3, sg = t / 192;
    int g = lane >> 4, d = lane & 15, ks = s * 4 + g;
    u32x4 row;
    #pragma unroll
    for (int cp = 0; cp < 4; ++cp) {
        float v0 = 0.f, v1 = 0.f;
        if (d < DOUT && ks < KNB) {
            v0 = w[((sg * CIN + 2 * cp    ) * KNB + ks) * DOUT + d];
            v1 = w[((sg * CIN + 2 * cp + 1) * KNB + ks) * DOUT + d];
        }
        row[cp] = pk_f16(v0, v1);
    }
    reinterpret_cast<u32x4*>(btab)[t] = row;
}

// grid = 512: b = bid&255, n-half = bid>>8 (bid and bid+256 land on same XCD).
// Stage full x[b] as fp16 [j][c] rows (16B) in LDS + zero sentinel row NSZ.
// Per 16-n tile: 3 gathered ds_read_b128 A-frags, 6 MFMAs (2 sites x K=96),
// per-row site select + bias at epilogue.
__global__ __launch_bounds__(1024) void latconv_kernel(
    const float* __restrict__ x, const int* __restrict__ nbh,
    const int* __restrict__ sub, const uint32_t* __restrict__ btab,
    const float* __restrict__ bias, float* __restrict__ out)
{
    __shared__ __align__(16) uint32_t xl[(NSZ + 1) * 4];   // 65552 B

    const int b    = blockIdx.x & 255;
    const int half = blockIdx.x >> 8;
    const int t    = threadIdx.x;
    const float* xb = x + (size_t)b * (CIN * NSZ);

    // ---- stage x[b] -> LDS (fp32 -> packed fp16, transpose to [j][c]) ----
    {
        const int j0 = 4 * t;
        f4 v[CIN];
        #pragma unroll
        for (int c = 0; c < CIN; ++c)
            v[c] = *reinterpret_cast<const f4*>(xb + c * NSZ + j0);   // coalesced 16B
        #pragma unroll
        for (int jj = 0; jj < 4; ++jj) {
            u32x4 row;
            #pragma unroll
            for (int cp = 0; cp < 4; ++cp)
                row[cp] = pk_f16(v[2 * cp][jj], v[2 * cp + 1][jj]);
            *reinterpret_cast<u32x4*>(&xl[(size_t)(j0 + jj) * 4]) = row;  // ds_write_b128
        }
    }
    if (t == 0) {   // zero sentinel row for padded k-slots
        u32x4 z = { 0, 0, 0, 0 };
        *reinterpret_cast<u32x4*>(&xl[(size_t)NSZ * 4]) = z;
    }

    const int lane = t & 63, wv = t >> 6;
    const int g = lane >> 4, r = lane & 15, d = r;

    // B-fragments: 2 sites x 3 K-steps, resident in 24 VGPRs for the whole kernel
    u32x4 bf[2][3];
    #pragma unroll
    for (int sg = 0; sg < 2; ++sg)
        #pragma unroll
        for (int s = 0; s < 3; ++s)
            bf[sg][s] = reinterpret_cast<const u32x4*>(btab)[(sg * 3 + s) * 64 + lane];

    const float bz0 = bias[d & 7];
    const float bz1 = bias[DOUT + (d & 7)];

    __syncthreads();

    const char* xlb = reinterpret_cast<const char*>(xl);
    #pragma unroll 2
    for (int tile = 0; tile < 8; ++tile) {
        const int n0 = half * 2048 + wv * 128 + tile * 16;

        // site ids for this lane's 4 output rows (rows g*4+reg)
        const int4 sv = *reinterpret_cast<const int4*>(sub + n0 + g * 4);

        // neighbor index per K-step: kslot = s*4+g; sentinel row for padded slots
        int js[3];
        #pragma unroll
        for (int s = 0; s < 3; ++s) {
            const int ks = s * 4 + g;
            js[s] = (ks < KNB) ? nbh[(n0 + r) * KNB + ks] : NSZ;
        }

        f4 a0 = { 0.f, 0.f, 0.f, 0.f };
        f4 a1 = { 0.f, 0.f, 0.f, 0.f };
        #pragma unroll
        for (int s = 0; s < 3; ++s) {
            const u32x4 av = *reinterpret_cast<const u32x4*>(xlb + ((size_t)(uint32_t)js[s] << 4));
            const v8fh af = __builtin_bit_cast(v8fh, av);
            a0 = __builtin_amdgcn_mfma_f32_16x16x32_f16(af, __builtin_bit_cast(v8fh, bf[0][s]), a0, 0, 0, 0);
            a1 = __builtin_amdgcn_mfma_f32_16x16x32_f16(af, __builtin_bit_cast(v8fh, bf[1][s]), a1, 0, 0, 0);
        }

        if (d < DOUT) {   // cols 8..15 are padding
            const int svv[4] = { sv.x, sv.y, sv.z, sv.w };
            f4 o;
            #pragma unroll
            for (int reg = 0; reg < 4; ++reg) {
                const float acc = svv[reg] ? a1[reg] : a0[reg];
                o[reg] = acc + (svv[reg] ? bz1 : bz0);
            }
            // rows g*4+reg are 4 consecutive n -> 16B store; lanes g=0..3 tile a 64B line
            *reinterpret_cast<f4*>(out + ((size_t)b * DOUT + d) * NSZ + n0 + g * 4) = o;
        }
    }
}

extern "C" void kernel_launch(void* const* d_in, const int* in_sizes, int n_in,
                              void* d_out, int out_size, void* d_ws, size_t ws_size,
                              hipStream_t stream) {
    const float* x    = (const float*)d_in[0];
    const int*   nbh  = (const int*)d_in[1];
    const int*   sub  = (const int*)d_in[2];
    const float* w    = (const float*)d_in[3];
    const float* bias = (const float*)d_in[4];
    float* out = (float*)d_out;
    uint32_t* btab = (uint32_t*)d_ws;   // 6144 B B-fragment table

    pack_bfrag_kernel<<<1, 384, 0, stream>>>(w, btab);
    latconv_kernel<<<2 * BSZ, 1024, 0, stream>>>(x, nbh, sub, btab, bias, out);
}

// Round 7
// 101.650 us; speedup vs baseline: 1.2586x; 1.0407x over previous
//
#include <hip/hip_runtime.h>
#include <stdint.h>
#include <stddef.h>

// Problem constants (fixed by the reference).
#define BSZ  256
#define NSZ  4096
#define CIN  8
#define KNB  9
#define DOUT 8
#define NSUB 2

typedef __fp16   fh2  __attribute__((ext_vector_type(2)));
typedef __fp16   v8fh __attribute__((ext_vector_type(8)));   // MFMA f16 A/B frag (4 VGPRs)
typedef float    f4   __attribute__((ext_vector_type(4)));
typedef uint32_t u32x4 __attribute__((ext_vector_type(4)));

#define BTAB_U32 (NSUB * 3 * 64 * 4)          // 1536 u32 = 6 KiB
#define BOFF     ((NSZ + 1) * 4)              // btab offset (u32 units) in LDS

static __device__ __forceinline__ uint32_t pk_f16(float a, float b) {
    fh2 h = __builtin_amdgcn_cvt_pkrtz(a, b);   // v_cvt_pkrtz_f16_f32
    return __builtin_bit_cast(uint32_t, h);
}

// grid = 512: b = bid&255, n-half = bid>>8 (bid and bid+256 land on same XCD).
// Single kernel: per block, build 6KB B-fragment table in LDS (384 threads) and
// stage full x[b] as fp16 [j][c] rows (16B) + zero sentinel row; one barrier.
// Per 16-n tile: 3 gathered ds_read_b128 A-frags, 6 MFMAs (2 sites x K=96),
// per-row site select + bias at epilogue.
__global__ __launch_bounds__(1024) void latconv_kernel(
    const float* __restrict__ x, const int* __restrict__ nbh,
    const int* __restrict__ sub, const float* __restrict__ w,
    const float* __restrict__ bias, float* __restrict__ out)
{
    __shared__ __align__(16) uint32_t xl[BOFF + BTAB_U32];   // 65552 + 6144 B

    const int b    = blockIdx.x & 255;
    const int half = blockIdx.x >> 8;
    const int t    = threadIdx.x;
    const float* xb = x + (size_t)b * (CIN * NSZ);

    // ---- build B-fragment table in LDS (same layout as old pack_bfrag_kernel) ----
    // entry t2 (0..383): lane = t2&63, s = (t2>>6)%3, sg = t2/192;
    // col d = lane&15, kslot = s*4 + (lane>>4); elem pair cp = channels (2cp, 2cp+1).
    if (t < NSUB * 3 * 64) {
        const int lane2 = t & 63, s = (t >> 6) % 3, sg = t / 192;
        const int g2 = lane2 >> 4, d2 = lane2 & 15, ks = s * 4 + g2;
        u32x4 row;
        #pragma unroll
        for (int cp = 0; cp < 4; ++cp) {
            float v0 = 0.f, v1 = 0.f;
            if (d2 < DOUT && ks < KNB) {
                v0 = w[((sg * CIN + 2 * cp    ) * KNB + ks) * DOUT + d2];
                v1 = w[((sg * CIN + 2 * cp + 1) * KNB + ks) * DOUT + d2];
            }
            row[cp] = pk_f16(v0, v1);
        }
        *reinterpret_cast<u32x4*>(&xl[BOFF + 4 * (size_t)t]) = row;
    }

    // ---- stage x[b] -> LDS (fp32 -> packed fp16, transpose to [j][c]) ----
    {
        const int j0 = 4 * t;
        f4 v[CIN];
        #pragma unroll
        for (int c = 0; c < CIN; ++c)
            v[c] = *reinterpret_cast<const f4*>(xb + c * NSZ + j0);   // coalesced 16B
        #pragma unroll
        for (int jj = 0; jj < 4; ++jj) {
            u32x4 row;
            #pragma unroll
            for (int cp = 0; cp < 4; ++cp)
                row[cp] = pk_f16(v[2 * cp][jj], v[2 * cp + 1][jj]);
            *reinterpret_cast<u32x4*>(&xl[(size_t)(j0 + jj) * 4]) = row;  // ds_write_b128
        }
    }
    if (t == 0) {   // zero sentinel row for padded k-slots
        u32x4 z = { 0, 0, 0, 0 };
        *reinterpret_cast<u32x4*>(&xl[(size_t)NSZ * 4]) = z;
    }

    const int lane = t & 63, wv = t >> 6;
    const int g = lane >> 4, r = lane & 15, d = r;

    const float bz0 = bias[d & 7];
    const float bz1 = bias[DOUT + (d & 7)];

    __syncthreads();

    // B-fragments: 2 sites x 3 K-steps, resident in 24 VGPRs for the whole kernel
    u32x4 bf[2][3];
    #pragma unroll
    for (int sg = 0; sg < 2; ++sg)
        #pragma unroll
        for (int s = 0; s < 3; ++s)
            bf[sg][s] = *reinterpret_cast<const u32x4*>(
                &xl[BOFF + 4 * (size_t)((sg * 3 + s) * 64 + lane)]);

    const char* xlb = reinterpret_cast<const char*>(xl);
    #pragma unroll 2
    for (int tile = 0; tile < 8; ++tile) {
        const int n0 = half * 2048 + wv * 128 + tile * 16;

        // site ids for this lane's 4 output rows (rows g*4+reg)
        const int4 sv = *reinterpret_cast<const int4*>(sub + n0 + g * 4);

        // neighbor index per K-step: kslot = s*4+g; sentinel row for padded slots
        int js[3];
        #pragma unroll
        for (int s = 0; s < 3; ++s) {
            const int ks = s * 4 + g;
            js[s] = (ks < KNB) ? nbh[(n0 + r) * KNB + ks] : NSZ;
        }

        f4 a0 = { 0.f, 0.f, 0.f, 0.f };
        f4 a1 = { 0.f, 0.f, 0.f, 0.f };
        #pragma unroll
        for (int s = 0; s < 3; ++s) {
            const u32x4 av = *reinterpret_cast<const u32x4*>(xlb + ((size_t)(uint32_t)js[s] << 4));
            const v8fh af = __builtin_bit_cast(v8fh, av);
            a0 = __builtin_amdgcn_mfma_f32_16x16x32_f16(af, __builtin_bit_cast(v8fh, bf[0][s]), a0, 0, 0, 0);
            a1 = __builtin_amdgcn_mfma_f32_16x16x32_f16(af, __builtin_bit_cast(v8fh, bf[1][s]), a1, 0, 0, 0);
        }

        if (d < DOUT) {   // cols 8..15 are padding
            const int svv[4] = { sv.x, sv.y, sv.z, sv.w };
            f4 o;
            #pragma unroll
            for (int reg = 0; reg < 4; ++reg) {
                const float acc = svv[reg] ? a1[reg] : a0[reg];
                o[reg] = acc + (svv[reg] ? bz1 : bz0);
            }
            // rows g*4+reg are 4 consecutive n -> 16B store; lanes g=0..3 tile a 64B line
            *reinterpret_cast<f4*>(out + ((size_t)b * DOUT + d) * NSZ + n0 + g * 4) = o;
        }
    }
}

extern "C" void kernel_launch(void* const* d_in, const int* in_sizes, int n_in,
                              void* d_out, int out_size, void* d_ws, size_t ws_size,
                              hipStream_t stream) {
    const float* x    = (const float*)d_in[0];
    const int*   nbh  = (const int*)d_in[1];
    const int*   sub  = (const int*)d_in[2];
    const float* w    = (const float*)d_in[3];
    const float* bias = (const float*)d_in[4];
    float* out = (float*)d_out;
    (void)d_ws; (void)ws_size;

    latconv_kernel<<<2 * BSZ, 1024, 0, stream>>>(x, nbh, sub, w, bias, out);
}